// Round 6
// baseline (243.354 us; speedup 1.0000x reference)
//
#include <hip/hip_runtime.h>

// SelfTensorProductS2Grid, v8: producer/consumer wave specialization.
//   grid[g,c] = sum_i Wt[g,i] X[i,c];  out[i,c] = sum_g Wf[g,i] grid[g,c]^2
// Both stages 32x32x16 (v7). v2-v7 ledger: W-latency null, occupancy-up
// regression, MFMA-count halving -6%. Remaining 68us of stall attributed to
// the intra-wave serial chain stage1->hazard->square->stage2 x11 at only
// 3 waves/SIMD. v8 splits each task across two waves: producer wave does
// stage1+square+pack and ds_writes bg; consumer wave ds_reads bg and runs
// stage2. Double-buffered LDS (16KB/block), one barrier per kc2 step.
// Producer stage1(k+1) overlaps consumer stage2(k) across waves; per-wave
// serial path halves; W-waits hide under the other role's MFMAs. MFMA
// totals, W traffic, and 3 blocks/CU unchanged vs v7.

#define NN    4096
#define L2D   49
#define CCH   128
#define GTOT  324
#define KC2   11              // g-chunks of 32 (11*32 = 352, pad from 324)

typedef __attribute__((ext_vector_type(8)))  short bf16x8;
typedef __attribute__((ext_vector_type(16))) float f32x16;

#define WT_SHORTS (KC2 * 4 * 64 * 8)      // [kc2][ki][lane][j] = 22528
#define WF_SHORTS (2 * KC2 * 2 * 64 * 8)  // [it][kc2][cc][lane][j] = 22528

__device__ __forceinline__ short f2bf(float f) {
    union { float f; unsigned u; } x; x.f = f;
    return (short)((x.u + 0x7fffu + ((x.u >> 16) & 1u)) >> 16);   // RNE
}

// pack two f32 -> two bf16 (RNE) in one VALU op
__device__ __forceinline__ unsigned cvtpk(float lo, float hi) {
    unsigned r;
    asm("v_cvt_pk_bf16_f32 %0, %1, %2" : "=v"(r) : "v"(lo), "v"(hi));
    return r;
}

// WtF[kc2][ki][lane][j]: A[m=lane&31][k=i=ki*16+(lane>>5)*8+j], where the
//   physical g of tile-row m is kc2*32 + gwc(m),
//   gwc(m) = ((m>>3)&1)*16 + ((m>>2)&1)*8 + (m>>4)*4 + (m&3).
// WfF[it][kc2][cc][lane][j]: A[m=i=it*32+(lane&31)][k: g=kc2*32+cc*16+
//   (lane>>5)*8+j]  (identity relabel on stage-2 side).
__global__ void prep_w_kernel(const float* __restrict__ Wt,
                              const float* __restrict__ Wf,
                              short* __restrict__ WtF,
                              short* __restrict__ WfF)
{
    int idx = blockIdx.x * 256 + threadIdx.x;
    if (idx < WT_SHORTS) {
        int j = idx & 7, lane = (idx >> 3) & 63, ki = (idx >> 9) & 3, kc2 = idx >> 11;
        int m = lane & 31, H = lane >> 5;
        int gwc = ((m >> 3) & 1) * 16 + ((m >> 2) & 1) * 8 + (m >> 4) * 4 + (m & 3);
        int g = kc2 * 32 + gwc;
        int i = ki * 16 + H * 8 + j;
        WtF[idx] = f2bf((g < GTOT && i < L2D) ? Wt[g * L2D + i] : 0.0f);
    } else if (idx < WT_SHORTS + WF_SHORTS) {
        int e = idx - WT_SHORTS;
        int j = e & 7, lane = (e >> 3) & 63, cc = (e >> 9) & 1;
        int u = e >> 10;                 // it*KC2 + kc2
        int kc2 = u % KC2, it = u / KC2;
        int m = lane & 31, H = lane >> 5;
        int i = it * 32 + m;
        int g = kc2 * 32 + cc * 16 + H * 8 + j;
        WfF[e] = f2bf((g < GTOT && i < L2D) ? Wf[g * L2D + i] : 0.0f);
    }
}

__global__ __launch_bounds__(256, 3)
void stp_mfma8_kernel(const float* __restrict__ inp,
                      const short* __restrict__ WtF,
                      const short* __restrict__ WfF,
                      float* __restrict__ out)
{
    // bg pipeline buffer: [buf][task_local][cq][cc][lane*8 bf16] = 16 KB
    __shared__ __attribute__((aligned(16))) short sBg[2][2][2][2][64 * 8];

    const int tid  = threadIdx.x;
    const int lane = tid & 63;
    const int wave = tid >> 6;        // 0,1 = producers; 2,3 = consumers
    const int m    = lane & 31;
    const int H    = lane >> 5;

    const bool prod = wave < 2;
    const int  tl   = prod ? wave : wave - 2;   // task-local index 0..1

    const int task = blockIdx.x * 2 + tl;        // 8192 tasks = (n, c-half)
    const int n    = task >> 1;
    const int h    = task & 1;

    // ---------------- producer persistent state: X B-fragments ----------------
    bf16x8 Bx[2][4];
    if (prod) {
        const float* __restrict__ Xn = inp + (size_t)n * (L2D * CCH);
        #pragma unroll
        for (int cq = 0; cq < 2; ++cq) {
            const int c = h * 64 + cq * 32 + m;
            #pragma unroll
            for (int ki = 0; ki < 4; ++ki) {
                union { bf16x8 v; unsigned u[4]; } b;
                #pragma unroll
                for (int p = 0; p < 4; ++p) {
                    const int i0 = ki * 16 + H * 8 + 2 * p;
                    float v0 = (i0     < L2D) ? Xn[(i0    ) * CCH + c] : 0.0f;
                    float v1 = (i0 + 1 < L2D) ? Xn[(i0 + 1) * CCH + c] : 0.0f;
                    b.u[p] = cvtpk(v0, v1);
                }
                Bx[cq][ki] = b.v;
            }
        }
    }

    // ---------------- consumer persistent state: accumulators ----------------
    f32x16 acc2[2][2];   // [it][cq]
    #pragma unroll
    for (int it = 0; it < 2; ++it)
        #pragma unroll
        for (int cq = 0; cq < 2; ++cq)
            acc2[it][cq] = (f32x16)(0.0f);

    // ---------------- software pipeline over g-chunks ----------------
    // slot k: producer computes bg for kc2=k into buf[k&1];
    //         consumer eats bg for kc2=k-1 from buf[(k-1)&1].
    #pragma unroll 1
    for (int k = 0; k <= KC2; ++k) {
        if (prod) {
            if (k < KC2) {
                bf16x8 Wtf[4];
                #pragma unroll
                for (int ki = 0; ki < 4; ++ki)
                    Wtf[ki] = *(const bf16x8*)&WtF[((k * 4 + ki) * 64 + lane) * 8];

                #pragma unroll
                for (int cq = 0; cq < 2; ++cq) {
                    f32x16 g = (f32x16)(0.0f);
                    #pragma unroll
                    for (int ki = 0; ki < 4; ++ki)
                        g = __builtin_amdgcn_mfma_f32_32x32x16_bf16(Wtf[ki], Bx[cq][ki], g, 0, 0, 0);

                    // square + pack: C/D regs {0-3,8-11} -> cc=0, {4-7,12-15} -> cc=1
                    union { bf16x8 v; unsigned u[4]; } bg0, bg1;
                    bg0.u[0] = cvtpk(g[0] * g[0],   g[1] * g[1]);
                    bg0.u[1] = cvtpk(g[2] * g[2],   g[3] * g[3]);
                    bg0.u[2] = cvtpk(g[8] * g[8],   g[9] * g[9]);
                    bg0.u[3] = cvtpk(g[10] * g[10], g[11] * g[11]);
                    bg1.u[0] = cvtpk(g[4] * g[4],   g[5] * g[5]);
                    bg1.u[1] = cvtpk(g[6] * g[6],   g[7] * g[7]);
                    bg1.u[2] = cvtpk(g[12] * g[12], g[13] * g[13]);
                    bg1.u[3] = cvtpk(g[14] * g[14], g[15] * g[15]);

                    *(bf16x8*)&sBg[k & 1][tl][cq][0][lane * 8] = bg0.v;
                    *(bf16x8*)&sBg[k & 1][tl][cq][1][lane * 8] = bg1.v;
                }
            }
        } else {
            if (k >= 1) {
                const int kc2 = k - 1;
                bf16x8 Wff[2][2];
                #pragma unroll
                for (int it = 0; it < 2; ++it)
                    #pragma unroll
                    for (int cc = 0; cc < 2; ++cc)
                        Wff[it][cc] = *(const bf16x8*)&WfF[(((it * KC2 + kc2) * 2 + cc) * 64 + lane) * 8];

                #pragma unroll
                for (int cq = 0; cq < 2; ++cq) {
                    bf16x8 bgr0 = *(const bf16x8*)&sBg[kc2 & 1][tl][cq][0][lane * 8];
                    bf16x8 bgr1 = *(const bf16x8*)&sBg[kc2 & 1][tl][cq][1][lane * 8];
                    #pragma unroll
                    for (int it = 0; it < 2; ++it) {
                        acc2[it][cq] = __builtin_amdgcn_mfma_f32_32x32x16_bf16(Wff[it][0], bgr0, acc2[it][cq], 0, 0, 0);
                        acc2[it][cq] = __builtin_amdgcn_mfma_f32_32x32x16_bf16(Wff[it][1], bgr1, acc2[it][cq], 0, 0, 0);
                    }
                }
            }
        }
        __syncthreads();
    }

    // ---------------- consumer store: C/D col=c, row i=it*32+(r&3)+8*(r>>2)+4H ----
    if (!prod) {
        float* __restrict__ On = out + (size_t)n * (L2D * CCH);
        #pragma unroll
        for (int it = 0; it < 2; ++it) {
            #pragma unroll
            for (int cq = 0; cq < 2; ++cq) {
                const int c = h * 64 + cq * 32 + m;
                #pragma unroll
                for (int r = 0; r < 16; ++r) {
                    const int i = it * 32 + (r & 3) + 8 * (r >> 2) + 4 * H;
                    if (i < L2D) On[i * CCH + c] = acc2[it][cq][r];
                }
            }
        }
    }
}

extern "C" void kernel_launch(void* const* d_in, const int* in_sizes, int n_in,
                              void* d_out, int out_size, void* d_ws, size_t ws_size,
                              hipStream_t stream) {
    const float* inp = (const float*)d_in[0];   // (4096, 49, 128) fp32
    const float* Wt  = (const float*)d_in[1];   // (18*18, 49) fp32
    const float* Wf  = (const float*)d_in[2];   // (18*18, 49) fp32
    float* out = (float*)d_out;                 // (4096, 49, 128) fp32

    short* WtF = (short*)d_ws;
    short* WfF = WtF + WT_SHORTS;               // total 90112 B of ws

    const int prep_threads = WT_SHORTS + WF_SHORTS;   // 45056
    prep_w_kernel<<<(prep_threads + 255) / 256, 256, 0, stream>>>(Wt, Wf, WtF, WfF);
    stp_mfma8_kernel<<<4096, 256, 0, stream>>>(inp, WtF, WfF, out);
}

// Round 9
// 240.289 us; speedup vs baseline: 1.0128x; 1.0128x over previous
//
#include <hip/hip_runtime.h>

// SelfTensorProductS2Grid, v10 (resubmit — round 8 was an infra failure, the
// kernel never ran): v7 MFMA core + X-in-LDS to fit 128 regs/wave
// -> 4 waves/SIMD.
//   grid[g,c] = sum_i Wt[g,i] X[i,c];  out[i,c] = sum_g Wf[g,i] grid[g,c]^2
// Model from v2-v7 ledger: per-wave lifetime ~25us INVARIANT across occupancy,
// W-source, MFMA/VMEM counts -> waves internally latency-limited, pipes idle;
// throughput = residents x work/25us. v6 (more residents, half work) lost;
// v10 raises residents at CONSTANT work/wave: evict the 32-reg resident Bx
// into block-shared LDS (bf16 X^T per n-tile, shared by the h=0/1 waves),
// re-read fragments per kc2 as contiguous b64s (slot-XOR swizzle -> read path
// conflict-free). 64 acc + 32 W + 16 transient + addr ~= 124 <= 128 cap.
// LDS 34.8KB x 4 blocks = 139KB <= 160 -> 16 waves/CU (was 12).
// v9 lesson applied: LDS handoff gets a real __syncthreads(); stores stay
// v7-style direct (proven).

#define NN    4096
#define L2D   49
#define CCH   128
#define GTOT  324
#define KC2   11              // g-chunks of 32 (11*32 = 352, pad from 324)

#define XSTR  68              // LDS i-stride in shorts (136 B, b64-aligned)

typedef __attribute__((ext_vector_type(4)))  short short4v;
typedef __attribute__((ext_vector_type(8)))  short bf16x8;
typedef __attribute__((ext_vector_type(16))) float f32x16;

#define WT_SHORTS (KC2 * 4 * 64 * 8)      // [kc2][ki][lane][j] = 22528
#define WF_SHORTS (2 * KC2 * 2 * 64 * 8)  // [it][kc2][cc][lane][j] = 22528

__device__ __forceinline__ short f2bf(float f) {
    union { float f; unsigned u; } x; x.f = f;
    return (short)((x.u + 0x7fffu + ((x.u >> 16) & 1u)) >> 16);   // RNE
}

// pack two f32 -> two bf16 (RNE) in one VALU op
__device__ __forceinline__ unsigned cvtpk(float lo, float hi) {
    unsigned r;
    asm("v_cvt_pk_bf16_f32 %0, %1, %2" : "=v"(r) : "v"(lo), "v"(hi));
    return r;
}

// WtF[kc2][ki][lane][j]: A[m=lane&31][k=i=ki*16+(lane>>5)*8+j], where the
//   physical g of tile-row m is kc2*32 + gwc(m),
//   gwc(m) = ((m>>3)&1)*16 + ((m>>2)&1)*8 + (m>>4)*4 + (m&3).
// WfF[it][kc2][cc][lane][j]: A[m=i=it*32+(lane&31)][k: g=kc2*32+cc*16+
//   (lane>>5)*8+j]  (identity relabel on stage-2 side).
__global__ void prep_w_kernel(const float* __restrict__ Wt,
                              const float* __restrict__ Wf,
                              short* __restrict__ WtF,
                              short* __restrict__ WfF)
{
    int idx = blockIdx.x * 256 + threadIdx.x;
    if (idx < WT_SHORTS) {
        int j = idx & 7, lane = (idx >> 3) & 63, ki = (idx >> 9) & 3, kc2 = idx >> 11;
        int m = lane & 31, H = lane >> 5;
        int gwc = ((m >> 3) & 1) * 16 + ((m >> 2) & 1) * 8 + (m >> 4) * 4 + (m & 3);
        int g = kc2 * 32 + gwc;
        int i = ki * 16 + H * 8 + j;
        WtF[idx] = f2bf((g < GTOT && i < L2D) ? Wt[g * L2D + i] : 0.0f);
    } else if (idx < WT_SHORTS + WF_SHORTS) {
        int e = idx - WT_SHORTS;
        int j = e & 7, lane = (e >> 3) & 63, cc = (e >> 9) & 1;
        int u = e >> 10;                 // it*KC2 + kc2
        int kc2 = u % KC2, it = u / KC2;
        int m = lane & 31, H = lane >> 5;
        int i = it * 32 + m;
        int g = kc2 * 32 + cc * 16 + H * 8 + j;
        WfF[e] = f2bf((g < GTOT && i < L2D) ? Wf[g * L2D + i] : 0.0f);
    }
}

__global__ __launch_bounds__(256, 4)
void stp_mfma10_kernel(const float* __restrict__ inp,
                       const short* __restrict__ WtF,
                       const short* __restrict__ WfF,
                       float* __restrict__ out)
{
    // X^T bf16 tiles for the block's two n: [nb][c 0..127][i 0..63 + pad],
    // 8-byte slots XOR-swizzled: slot8' = slot8 ^ ((c>>4)&1).
    __shared__ __attribute__((aligned(16))) short sXT[2][CCH * XSTR];  // 34816 B

    const int tid  = threadIdx.x;
    const int lane = tid & 63;
    const int wave = tid >> 6;

    const int n0 = blockIdx.x * 2;

    // ---- cooperative staging: X[n0..n0+1][i<49][c] -> LDS X^T (bf16) ----
    // q decomposition covers every (nb, i in [0,64), c) cell exactly once;
    // i >= 49 cells are zero-filled (K-padding for the MFMA).
    #pragma unroll 4
    for (int pass = 0; pass < 16; ++pass) {
        const int q   = pass * 256 + tid;     // [0, 4096)
        const int c4i = q & 31;
        const int i   = (q >> 5) & 63;
        const int nb  = q >> 11;
        short v0 = 0, v1 = 0, v2 = 0, v3 = 0;
        if (i < L2D) {
            const float4 x = *(const float4*)&inp[((size_t)(n0 + nb) * L2D + i) * CCH + c4i * 4];
            v0 = f2bf(x.x); v1 = f2bf(x.y); v2 = f2bf(x.z); v3 = f2bf(x.w);
        }
        const int s8b = i >> 2;
        const int il  = i & 3;
        short* dst = &sXT[nb][0];
        {
            const int c = c4i * 4 + 0;
            dst[c * XSTR + ((s8b ^ ((c >> 4) & 1)) << 2) + il] = v0;
        }
        {
            const int c = c4i * 4 + 1;
            dst[c * XSTR + ((s8b ^ ((c >> 4) & 1)) << 2) + il] = v1;
        }
        {
            const int c = c4i * 4 + 2;
            dst[c * XSTR + ((s8b ^ ((c >> 4) & 1)) << 2) + il] = v2;
        }
        {
            const int c = c4i * 4 + 3;
            dst[c * XSTR + ((s8b ^ ((c >> 4) & 1)) << 2) + il] = v3;
        }
    }
    __syncthreads();

    const int m  = lane & 31;       // col index within 32-tile
    const int H  = lane >> 5;       // k-half
    const int sw = (m >> 4) & 1;    // slot swizzle key (== (cl>>4)&1)

    const int nb = wave >> 1;       // which n of the block's pair
    const int h  = wave & 1;        // c-half
    const int n  = n0 + nb;

    const short* __restrict__ xb = &sXT[nb][0];

    f32x16 acc2[2][2];   // [it][cq]
    #pragma unroll
    for (int it = 0; it < 2; ++it)
        #pragma unroll
        for (int cq = 0; cq < 2; ++cq)
            acc2[it][cq] = (f32x16)(0.0f);

    #pragma unroll 1
    for (int kc2 = 0; kc2 < KC2; ++kc2) {
        // W fragments for this g-chunk (16B coalesced, L1/L2-resident)
        bf16x8 Wtf[4];
        #pragma unroll
        for (int ki = 0; ki < 4; ++ki)
            Wtf[ki] = *(const bf16x8*)&WtF[((kc2 * 4 + ki) * 64 + lane) * 8];
        bf16x8 Wff[2][2];
        #pragma unroll
        for (int it = 0; it < 2; ++it)
            #pragma unroll
            for (int cc = 0; cc < 2; ++cc)
                Wff[it][cc] = *(const bf16x8*)&WfF[(((it * KC2 + kc2) * 2 + cc) * 64 + lane) * 8];

        #pragma unroll
        for (int cq = 0; cq < 2; ++cq) {
            const int cl = h * 64 + cq * 32 + m;
            // X B-fragments from LDS: i = ki*16 + H*8 + jh*4 + (0..3),
            // two b64 reads per fragment at swizzled slots (conflict-free)
            f32x16 g = (f32x16)(0.0f);
            #pragma unroll
            for (int ki = 0; ki < 4; ++ki) {
                union { bf16x8 v; short4v q[2]; } b;
                #pragma unroll
                for (int jh = 0; jh < 2; ++jh) {
                    const int s8 = (ki * 4 + H * 2 + jh) ^ sw;
                    b.q[jh] = *(const short4v*)&xb[cl * XSTR + s8 * 4];
                }
                g = __builtin_amdgcn_mfma_f32_32x32x16_bf16(Wtf[ki], b.v, g, 0, 0, 0);
            }

            // square + pack: C/D regs {0-3,8-11} -> cc=0, {4-7,12-15} -> cc=1
            union { bf16x8 v; unsigned u[4]; } bg0, bg1;
            bg0.u[0] = cvtpk(g[0] * g[0],   g[1] * g[1]);
            bg0.u[1] = cvtpk(g[2] * g[2],   g[3] * g[3]);
            bg0.u[2] = cvtpk(g[8] * g[8],   g[9] * g[9]);
            bg0.u[3] = cvtpk(g[10] * g[10], g[11] * g[11]);
            bg1.u[0] = cvtpk(g[4] * g[4],   g[5] * g[5]);
            bg1.u[1] = cvtpk(g[6] * g[6],   g[7] * g[7]);
            bg1.u[2] = cvtpk(g[12] * g[12], g[13] * g[13]);
            bg1.u[3] = cvtpk(g[14] * g[14], g[15] * g[15]);

            // stage 2: out[i, c] += Wf[:, g-chunk] * grid^2
            #pragma unroll
            for (int it = 0; it < 2; ++it) {
                acc2[it][cq] = __builtin_amdgcn_mfma_f32_32x32x16_bf16(Wff[it][0], bg0.v, acc2[it][cq], 0, 0, 0);
                acc2[it][cq] = __builtin_amdgcn_mfma_f32_32x32x16_bf16(Wff[it][1], bg1.v, acc2[it][cq], 0, 0, 0);
            }
        }
    }

    // ---- store: C/D col=c, row i = it*32 + (r&3) + 8*(r>>2) + 4*H ----
    float* __restrict__ On = out + (size_t)n * (L2D * CCH);
    #pragma unroll
    for (int it = 0; it < 2; ++it) {
        #pragma unroll
        for (int cq = 0; cq < 2; ++cq) {
            const int c = h * 64 + cq * 32 + m;
            #pragma unroll
            for (int r = 0; r < 16; ++r) {
                const int i = it * 32 + (r & 3) + 8 * (r >> 2) + 4 * H;
                if (i < L2D) On[i * CCH + c] = acc2[it][cq][r];
            }
        }
    }
}

extern "C" void kernel_launch(void* const* d_in, const int* in_sizes, int n_in,
                              void* d_out, int out_size, void* d_ws, size_t ws_size,
                              hipStream_t stream) {
    const float* inp = (const float*)d_in[0];   // (4096, 49, 128) fp32
    const float* Wt  = (const float*)d_in[1];   // (18*18, 49) fp32
    const float* Wf  = (const float*)d_in[2];   // (18*18, 49) fp32
    float* out = (float*)d_out;                 // (4096, 49, 128) fp32

    short* WtF = (short*)d_ws;
    short* WfF = WtF + WT_SHORTS;               // total 90112 B of ws

    const int prep_threads = WT_SHORTS + WF_SHORTS;   // 45056
    prep_w_kernel<<<(prep_threads + 255) / 256, 256, 0, stream>>>(Wt, Wf, WtF, WfF);
    stp_mfma10_kernel<<<2048, 256, 0, stream>>>(inp, WtF, WfF, out);
}